// Round 11
// baseline (141.402 us; speedup 1.0000x reference)
//
#include <hip/hip_runtime.h>
#include <hip/hip_bf16.h>

#define IN_F 4096
#define LOCAL_F 128
#define KSZ 64
#define STRIDE_ 32
#define FOLDS 127
#define BATCH_ 4096
#define OUT_F (FOLDS * LOCAL_F)    // 16256
#define WN (FOLDS * LOCAL_F * KSZ) // 1040384

#define ROWS 16
#define FPB 8                       // folds per tile
#define LDSW (FPB * LOCAL_F + 4)    // 1028 floats: +4 pad -> conflict-free b128

typedef __attribute__((ext_vector_type(8))) short bf16x8;
typedef __attribute__((ext_vector_type(8))) unsigned short u16x8;
typedef __attribute__((ext_vector_type(4))) float f32x4;

__device__ __forceinline__ unsigned short f2bf(float f) {
    unsigned u = __builtin_bit_cast(unsigned, f);
    u += 0x7fffu + ((u >> 16) & 1u);   // round-to-nearest-even
    return (unsigned short)(u >> 16);
}

// ---- prep: W fp32 -> bf16 (4 MB read / 2 MB write) ----
__global__ __launch_bounds__(256)
void wprep_kernel(const float* __restrict__ W, unsigned short* __restrict__ Wbf) {
    int i = (blockIdx.x * 256 + threadIdx.x) * 8;
    if (i >= WN) return;
    float4 a = *reinterpret_cast<const float4*>(W + i);
    float4 c = *reinterpret_cast<const float4*>(W + i + 4);
    u16x8 s;
    s[0] = f2bf(a.x); s[1] = f2bf(a.y); s[2] = f2bf(a.z); s[3] = f2bf(a.w);
    s[4] = f2bf(c.x); s[5] = f2bf(c.y); s[6] = f2bf(c.z); s[7] = f2bf(c.w);
    *reinterpret_cast<u16x8*>(Wbf + i) = s;
}

// ---- main: 512 PERSISTENT blocks (2/CU); each sweeps 8 contiguous 64-KB output
// tiles in ascending address order (strictly linear write cursor per block).
// x loads NONTEMPORAL (no L2 allocation -> L2 stays clean for the write stream).
// Plain stores: full-line write-combine in L2, dirty drain in address order.
__global__ __launch_bounds__(256, 2)
void ll_main(const float* __restrict__ x,
             const unsigned short* __restrict__ Wbf,
             const float* __restrict__ b,
             float* __restrict__ out) {
    __shared__ float os[ROWS][LDSW];

    const int l = blockIdx.x;             // 0..511
    const int j = l & 7;                  // XCD (round-robin dispatch)
    const int k = l >> 3;                 // 0..63: block index within XCD

    const int wave = threadIdx.x >> 6;
    const int lane = threadIdx.x & 63;
    const int l16 = lane & 15;
    const int g   = lane >> 4;

    for (int i = 0; i < 8; ++i) {
        const int v   = (j * 64 + k) * 8 + i;   // tile 0..4095, contiguous per block
        const int rg  = v >> 4;                 // 16-row band
        const int fqb = v & 15;                 // fold band (fastest -> linear addresses)
        const int row0 = rg * ROWS;

        if (i != 0) __syncthreads();            // os free from previous epilogue

        #pragma unroll
        for (int p = 0; p < 2; ++p) {
            const int fl = wave * 2 + p;        // fold-local 0..7
            const int f  = fqb * FPB + fl;
            if (f < FOLDS) {
                // x fragments (NT loads): x[row0+l16][f*32 + ks*32 + g*8 + 0..7]
                const float* xp = x + (size_t)(row0 + l16) * IN_F + f * STRIDE_ + g * 8;
                f32x4 xa0 = __builtin_nontemporal_load(reinterpret_cast<const f32x4*>(xp));
                f32x4 xa1 = __builtin_nontemporal_load(reinterpret_cast<const f32x4*>(xp + 4));
                f32x4 xb0 = __builtin_nontemporal_load(reinterpret_cast<const f32x4*>(xp + 32));
                f32x4 xb1 = __builtin_nontemporal_load(reinterpret_cast<const f32x4*>(xp + 36));

                // W fragments: W[f][nt*16 + l16][ks*32 + g*8 + 0..7] (2 MB bf16, L2-resident)
                const unsigned short* Wf = Wbf + (size_t)f * (LOCAL_F * KSZ) + l16 * KSZ + g * 8;
                bf16x8 wf[2][8];
                #pragma unroll
                for (int nt = 0; nt < 8; ++nt) {
                    wf[0][nt] = *reinterpret_cast<const bf16x8*>(Wf + nt * 16 * KSZ);
                    wf[1][nt] = *reinterpret_cast<const bf16x8*>(Wf + nt * 16 * KSZ + 32);
                }

                bf16x8 af0, af1;
                af0[0] = (short)f2bf(xa0[0]); af0[1] = (short)f2bf(xa0[1]);
                af0[2] = (short)f2bf(xa0[2]); af0[3] = (short)f2bf(xa0[3]);
                af0[4] = (short)f2bf(xa1[0]); af0[5] = (short)f2bf(xa1[1]);
                af0[6] = (short)f2bf(xa1[2]); af0[7] = (short)f2bf(xa1[3]);
                af1[0] = (short)f2bf(xb0[0]); af1[1] = (short)f2bf(xb0[1]);
                af1[2] = (short)f2bf(xb0[2]); af1[3] = (short)f2bf(xb0[3]);
                af1[4] = (short)f2bf(xb1[0]); af1[5] = (short)f2bf(xb1[1]);
                af1[6] = (short)f2bf(xb1[2]); af1[7] = (short)f2bf(xb1[3]);

                // MFMA: D = W x X^T ; lane holds D[feat = nt*16 + 4g + ii][batch = l16]
                f32x4 acc[8];
                #pragma unroll
                for (int nt = 0; nt < 8; ++nt) acc[nt] = (f32x4){0.f, 0.f, 0.f, 0.f};
                #pragma unroll
                for (int nt = 0; nt < 8; ++nt)
                    acc[nt] = __builtin_amdgcn_mfma_f32_16x16x32_bf16(wf[0][nt], af0, acc[nt], 0, 0, 0);
                #pragma unroll
                for (int nt = 0; nt < 8; ++nt)
                    acc[nt] = __builtin_amdgcn_mfma_f32_16x16x32_bf16(wf[1][nt], af1, acc[nt], 0, 0, 0);

                // bias + stage to LDS: os[row=l16][fl*128 + nt*16 + 4g + 0..3]
                #pragma unroll
                for (int nt = 0; nt < 8; ++nt) {
                    f32x4 bv = *reinterpret_cast<const f32x4*>(b + (size_t)f * LOCAL_F + nt * 16 + 4 * g);
                    f32x4 vv = acc[nt] + bv;
                    *reinterpret_cast<f32x4*>(&os[l16][fl * LOCAL_F + nt * 16 + 4 * g]) = vv;
                }
            }
        }
        __syncthreads();

        // dense epilogue: per row, 256 threads write one 4-KB contiguous PLAIN burst
        const int t = threadIdx.x;
        const int colbase = fqb * (FPB * LOCAL_F);   // fqb*1024
        const int col = colbase + 4 * t;
        #pragma unroll
        for (int r = 0; r < ROWS; ++r) {
            if (col < OUT_F) {
                f32x4 vv = *reinterpret_cast<const f32x4*>(&os[r][4 * t]);
                *reinterpret_cast<f32x4*>(out + (size_t)(row0 + r) * OUT_F + col) = vv;
            }
        }
    }
}

extern "C" void kernel_launch(void* const* d_in, const int* in_sizes, int n_in,
                              void* d_out, int out_size, void* d_ws, size_t ws_size,
                              hipStream_t stream) {
    const float* x = (const float*)d_in[0];
    const float* W = (const float*)d_in[1];
    const float* b = (const float*)d_in[2];
    float* out = (float*)d_out;
    unsigned short* Wbf = (unsigned short*)d_ws;

    wprep_kernel<<<(WN / 8 + 255) / 256, 256, 0, stream>>>(W, Wbf);
    ll_main<<<dim3(512), 256, 0, stream>>>(x, Wbf, b, out);
}

// Round 12
// 134.102 us; speedup vs baseline: 1.0544x; 1.0544x over previous
//
#include <hip/hip_runtime.h>
#include <hip/hip_bf16.h>

#define IN_F 4096
#define LOCAL_F 128
#define KSZ 64
#define STRIDE_ 32
#define FOLDS 127
#define BATCH_ 4096
#define OUT_F (FOLDS * LOCAL_F)    // 16256
#define WN (FOLDS * LOCAL_F * KSZ) // 1040384

#define ROWS 16
#define FPB 8                       // folds per block
#define LDSW (FPB * LOCAL_F + 4)    // 1028 floats: +4 pad -> conflict-free b128

typedef __attribute__((ext_vector_type(8))) short bf16x8;
typedef __attribute__((ext_vector_type(8))) unsigned short u16x8;
typedef __attribute__((ext_vector_type(4))) float f32x4;

__device__ __forceinline__ unsigned short f2bf(float f) {
    unsigned u = __builtin_bit_cast(unsigned, f);
    u += 0x7fffu + ((u >> 16) & 1u);   // round-to-nearest-even
    return (unsigned short)(u >> 16);
}

// ---- prep: W fp32 -> bf16 (4 MB read / 2 MB write) ----
__global__ __launch_bounds__(256)
void wprep_kernel(const float* __restrict__ W, unsigned short* __restrict__ Wbf) {
    int i = (blockIdx.x * 256 + threadIdx.x) * 8;
    if (i >= WN) return;
    float4 a = *reinterpret_cast<const float4*>(W + i);
    float4 c = *reinterpret_cast<const float4*>(W + i + 4);
    u16x8 s;
    s[0] = f2bf(a.x); s[1] = f2bf(a.y); s[2] = f2bf(a.z); s[3] = f2bf(a.w);
    s[4] = f2bf(c.x); s[5] = f2bf(c.y); s[6] = f2bf(c.z); s[7] = f2bf(c.w);
    *reinterpret_cast<u16x8*>(Wbf + i) = s;
}

// ---- main: R9 structure; x reads DEVICE-SCOPE (sc1) -> bypass/skip L2 so the
// XCD L2 holds only the write stream (fill-kernel regime). Plain dense stores.
__global__ __launch_bounds__(256, 2)
void ll_main(const float* __restrict__ x,
             const unsigned short* __restrict__ Wbf,
             const float* __restrict__ b,
             float* __restrict__ out) {
    __shared__ float os[ROWS][LDSW];

    const int l   = blockIdx.x;           // 0..4095
    const int j   = l & 7;                // XCD (round-robin dispatch)
    const int s   = l >> 3;               // 0..511, ascending per XCD
    const int rg  = j * 32 + (s >> 4);    // XCD-local contiguous row slab
    const int fqb = s & 15;               // fold band fastest -> linear addresses
    const int row0 = rg * ROWS;

    const int wave = threadIdx.x >> 6;
    const int lane = threadIdx.x & 63;
    const int l16 = lane & 15;
    const int g   = lane >> 4;

    const int f0 = fqb * FPB + wave * 2;          // <= 126 always
    const int f1raw = f0 + 1;
    const int f1 = f1raw > FOLDS - 1 ? FOLDS - 1 : f1raw;  // clamp tail (guarded at store)

    // ---- all 8 x-loads in ONE asm block, device-scope, single waitcnt inside ----
    const float* xr = x + (size_t)(row0 + l16) * IN_F + g * 8;
    const float* p00 = xr + f0 * STRIDE_;
    const float* p02 = p00 + 32;
    const float* p10 = xr + f1 * STRIDE_;
    const float* p12 = p10 + 32;

    f32x4 A0, A1, A2, A3, B0, B1, B2, B3;
    asm volatile(
        "global_load_dwordx4 %0, %8, off sc1\n\t"
        "global_load_dwordx4 %1, %8, off offset:16 sc1\n\t"
        "global_load_dwordx4 %2, %9, off sc1\n\t"
        "global_load_dwordx4 %3, %9, off offset:16 sc1\n\t"
        "global_load_dwordx4 %4, %10, off sc1\n\t"
        "global_load_dwordx4 %5, %10, off offset:16 sc1\n\t"
        "global_load_dwordx4 %6, %11, off sc1\n\t"
        "global_load_dwordx4 %7, %11, off offset:16 sc1\n\t"
        "s_waitcnt vmcnt(0)"
        : "=&v"(A0), "=&v"(A1), "=&v"(A2), "=&v"(A3),
          "=&v"(B0), "=&v"(B1), "=&v"(B2), "=&v"(B3)
        : "v"(p00), "v"(p02), "v"(p10), "v"(p12)
        : "memory");

    #pragma unroll
    for (int p = 0; p < 2; ++p) {
        const int fl = wave * 2 + p;      // fold-local 0..7
        const int fc = p == 0 ? f0 : f1;  // clamped fold (garbage cols guarded below)

        bf16x8 af0, af1;
        {
            const f32x4 va0 = p == 0 ? A0 : B0;
            const f32x4 va1 = p == 0 ? A1 : B1;
            const f32x4 vb0 = p == 0 ? A2 : B2;
            const f32x4 vb1 = p == 0 ? A3 : B3;
            af0[0] = (short)f2bf(va0[0]); af0[1] = (short)f2bf(va0[1]);
            af0[2] = (short)f2bf(va0[2]); af0[3] = (short)f2bf(va0[3]);
            af0[4] = (short)f2bf(va1[0]); af0[5] = (short)f2bf(va1[1]);
            af0[6] = (short)f2bf(va1[2]); af0[7] = (short)f2bf(va1[3]);
            af1[0] = (short)f2bf(vb0[0]); af1[1] = (short)f2bf(vb0[1]);
            af1[2] = (short)f2bf(vb0[2]); af1[3] = (short)f2bf(vb0[3]);
            af1[4] = (short)f2bf(vb1[0]); af1[5] = (short)f2bf(vb1[1]);
            af1[6] = (short)f2bf(vb1[2]); af1[7] = (short)f2bf(vb1[3]);
        }

        // W fragments: W[fc][nt*16 + l16][ks*32 + g*8 + 0..7] (2 MB bf16, L2-resident)
        const unsigned short* Wf = Wbf + (size_t)fc * (LOCAL_F * KSZ) + l16 * KSZ + g * 8;
        bf16x8 wf[2][8];
        #pragma unroll
        for (int nt = 0; nt < 8; ++nt) {
            wf[0][nt] = *reinterpret_cast<const bf16x8*>(Wf + nt * 16 * KSZ);
            wf[1][nt] = *reinterpret_cast<const bf16x8*>(Wf + nt * 16 * KSZ + 32);
        }

        // MFMA: D = W x X^T ; lane holds D[feat = nt*16 + 4g + i][batch = l16]
        f32x4 acc[8];
        #pragma unroll
        for (int nt = 0; nt < 8; ++nt) acc[nt] = (f32x4){0.f, 0.f, 0.f, 0.f};
        #pragma unroll
        for (int nt = 0; nt < 8; ++nt)
            acc[nt] = __builtin_amdgcn_mfma_f32_16x16x32_bf16(wf[0][nt], af0, acc[nt], 0, 0, 0);
        #pragma unroll
        for (int nt = 0; nt < 8; ++nt)
            acc[nt] = __builtin_amdgcn_mfma_f32_16x16x32_bf16(wf[1][nt], af1, acc[nt], 0, 0, 0);

        // bias + stage to LDS: os[row=l16][fl*128 + nt*16 + 4g + 0..3]
        #pragma unroll
        for (int nt = 0; nt < 8; ++nt) {
            f32x4 bv = *reinterpret_cast<const f32x4*>(b + (size_t)fc * LOCAL_F + nt * 16 + 4 * g);
            f32x4 vv = acc[nt] + bv;
            *reinterpret_cast<f32x4*>(&os[l16][fl * LOCAL_F + nt * 16 + 4 * g]) = vv;
        }
    }
    __syncthreads();

    // dense epilogue: per row, 256 threads write one 4-KB contiguous PLAIN burst
    const int t = threadIdx.x;
    const int colbase = fqb * (FPB * LOCAL_F);   // fqb*1024
    const int col = colbase + 4 * t;
    #pragma unroll
    for (int r = 0; r < ROWS; ++r) {
        if (col < OUT_F) {
            f32x4 vv = *reinterpret_cast<const f32x4*>(&os[r][4 * t]);
            *reinterpret_cast<f32x4*>(out + (size_t)(row0 + r) * OUT_F + col) = vv;
        }
    }
}

extern "C" void kernel_launch(void* const* d_in, const int* in_sizes, int n_in,
                              void* d_out, int out_size, void* d_ws, size_t ws_size,
                              hipStream_t stream) {
    const float* x = (const float*)d_in[0];
    const float* W = (const float*)d_in[1];
    const float* b = (const float*)d_in[2];
    float* out = (float*)d_out;
    unsigned short* Wbf = (unsigned short*)d_ws;

    wprep_kernel<<<(WN / 8 + 255) / 256, 256, 0, stream>>>(W, Wbf);
    ll_main<<<dim3(4096), 256, 0, stream>>>(x, Wbf, b, out);
}

// Round 13
// 116.841 us; speedup vs baseline: 1.2102x; 1.1477x over previous
//
#include <hip/hip_runtime.h>
#include <hip/hip_bf16.h>

#define IN_F 4096
#define LOCAL_F 128
#define KSZ 64
#define STRIDE_ 32
#define FOLDS 127
#define BATCH_ 4096
#define OUT_F (FOLDS * LOCAL_F)    // 16256
#define WN (FOLDS * LOCAL_F * KSZ) // 1040384

typedef __attribute__((ext_vector_type(8))) short bf16x8;
typedef __attribute__((ext_vector_type(8))) unsigned short u16x8;
typedef __attribute__((ext_vector_type(4))) float f32x4;

__device__ __forceinline__ unsigned short f2bf(float f) {
    unsigned u = __builtin_bit_cast(unsigned, f);
    u += 0x7fffu + ((u >> 16) & 1u);   // round-to-nearest-even
    return (unsigned short)(u >> 16);
}

// ---- prep: W fp32 -> bf16 (4 MB read / 2 MB write, ~1.5 us) ----
__global__ __launch_bounds__(256)
void wprep_kernel(const float* __restrict__ W, unsigned short* __restrict__ Wbf) {
    int i = (blockIdx.x * 256 + threadIdx.x) * 8;
    if (i >= WN) return;
    float4 a = *reinterpret_cast<const float4*>(W + i);
    float4 c = *reinterpret_cast<const float4*>(W + i + 4);
    u16x8 s;
    s[0] = f2bf(a.x); s[1] = f2bf(a.y); s[2] = f2bf(a.z); s[3] = f2bf(a.w);
    s[4] = f2bf(c.x); s[5] = f2bf(c.y); s[6] = f2bf(c.z); s[7] = f2bf(c.w);
    *reinterpret_cast<u16x8*>(Wbf + i) = s;
}

// ---- main: R4 structure + direct fp32 x + 1-fold x-prefetch pipeline ----
// block = 16 rows x 32 folds (grid 256x4); wave w owns folds fq*32 + w + 4j.
// NT stores spread across the whole block lifetime (8 bursts/wave).
// x for fold j+1 prefetched before computing fold j (hides ~900cy HBM latency).
__global__ __launch_bounds__(256, 4)
void ll_main(const float* __restrict__ x,
             const unsigned short* __restrict__ Wbf,
             const float* __restrict__ b,
             float* __restrict__ out) {
    const int rg = blockIdx.x;            // 0..255: 16-row batch group
    const int fq = blockIdx.y;            // 0..3:  32-fold quarter
    const int row0 = rg * 16;

    const int wave = threadIdx.x >> 6;
    const int lane = threadIdx.x & 63;
    const int l16 = lane & 15;
    const int g   = lane >> 4;

    const float* xrow = x + (size_t)(row0 + l16) * IN_F + g * 8;
    float*       orow = out + (size_t)(row0 + l16) * OUT_F + 4 * g;

    // ---- prefetch x for j = 0 ----
    const int ffirst = fq * 32 + wave;
    f32x4 nxa0, nxa1, nxb0, nxb1;
    {
        const float* p = xrow + ffirst * STRIDE_;
        nxa0 = *reinterpret_cast<const f32x4*>(p);
        nxa1 = *reinterpret_cast<const f32x4*>(p + 4);
        nxb0 = *reinterpret_cast<const f32x4*>(p + 32);
        nxb1 = *reinterpret_cast<const f32x4*>(p + 36);
    }

    #pragma unroll
    for (int j = 0; j < 8; ++j) {
        const int f = fq * 32 + wave + 4 * j;
        if (f >= FOLDS) break;            // only fq=3, wave=3, j=7

        // consume prefetched x
        f32x4 xa0 = nxa0, xa1 = nxa1, xb0 = nxb0, xb1 = nxb1;

        // ---- prefetch x for j+1 (issued before any compute of fold j) ----
        if (j < 7 && f + 4 < FOLDS) {
            const float* p = xrow + (f + 4) * STRIDE_;
            nxa0 = *reinterpret_cast<const f32x4*>(p);
            nxa1 = *reinterpret_cast<const f32x4*>(p + 4);
            nxb0 = *reinterpret_cast<const f32x4*>(p + 32);
            nxb1 = *reinterpret_cast<const f32x4*>(p + 36);
        }

        // ---- convert x to bf16 fragments ----
        bf16x8 af0, af1;
        af0[0] = (short)f2bf(xa0[0]); af0[1] = (short)f2bf(xa0[1]);
        af0[2] = (short)f2bf(xa0[2]); af0[3] = (short)f2bf(xa0[3]);
        af0[4] = (short)f2bf(xa1[0]); af0[5] = (short)f2bf(xa1[1]);
        af0[6] = (short)f2bf(xa1[2]); af0[7] = (short)f2bf(xa1[3]);
        af1[0] = (short)f2bf(xb0[0]); af1[1] = (short)f2bf(xb0[1]);
        af1[2] = (short)f2bf(xb0[2]); af1[3] = (short)f2bf(xb0[3]);
        af1[4] = (short)f2bf(xb1[0]); af1[5] = (short)f2bf(xb1[1]);
        af1[6] = (short)f2bf(xb1[2]); af1[7] = (short)f2bf(xb1[3]);

        // ---- W fragments + MFMA, ks-staged (keeps wf live set at 32 VGPR) ----
        f32x4 acc[8];
        #pragma unroll
        for (int nt = 0; nt < 8; ++nt) acc[nt] = (f32x4){0.f, 0.f, 0.f, 0.f};

        const unsigned short* Wf = Wbf + (size_t)f * (LOCAL_F * KSZ) + l16 * KSZ + g * 8;
        {
            bf16x8 wf[8];
            #pragma unroll
            for (int nt = 0; nt < 8; ++nt)
                wf[nt] = *reinterpret_cast<const bf16x8*>(Wf + nt * 16 * KSZ);
            #pragma unroll
            for (int nt = 0; nt < 8; ++nt)
                acc[nt] = __builtin_amdgcn_mfma_f32_16x16x32_bf16(wf[nt], af0, acc[nt], 0, 0, 0);
        }
        {
            bf16x8 wf[8];
            #pragma unroll
            for (int nt = 0; nt < 8; ++nt)
                wf[nt] = *reinterpret_cast<const bf16x8*>(Wf + nt * 16 * KSZ + 32);
            #pragma unroll
            for (int nt = 0; nt < 8; ++nt)
                acc[nt] = __builtin_amdgcn_mfma_f32_16x16x32_bf16(wf[nt], af1, acc[nt], 0, 0, 0);
        }

        // ---- bias + NT stores (spread: one 8-instr burst per fold) ----
        // lane writes feat f*128 + nt*16 + 4g + 0..3 in its own batch row
        #pragma unroll
        for (int nt = 0; nt < 8; ++nt) {
            f32x4 bv = *reinterpret_cast<const f32x4*>(b + (size_t)f * LOCAL_F + nt * 16 + 4 * g);
            f32x4 v = acc[nt] + bv;
            __builtin_nontemporal_store(v,
                reinterpret_cast<f32x4*>(orow + (size_t)f * LOCAL_F + nt * 16));
        }
    }
}

extern "C" void kernel_launch(void* const* d_in, const int* in_sizes, int n_in,
                              void* d_out, int out_size, void* d_ws, size_t ws_size,
                              hipStream_t stream) {
    const float* x = (const float*)d_in[0];
    const float* W = (const float*)d_in[1];
    const float* b = (const float*)d_in[2];
    float* out = (float*)d_out;
    unsigned short* Wbf = (unsigned short*)d_ws;

    wprep_kernel<<<(WN / 8 + 255) / 256, 256, 0, stream>>>(W, Wbf);
    dim3 grid(BATCH_ / 16, 4);
    ll_main<<<grid, 256, 0, stream>>>(x, Wbf, b, out);
}